// Round 7
// baseline (35460.205 us; speedup 1.0000x reference)
//
#include <hip/hip_runtime.h>
#include <math.h>

#define B 256
#define H 512
#define T 256
#define V 28
#define G4 2048  // 4*H

#define OUT_MU 1835008            // T*B*V
#define OUT_LV (1835008+131072)

typedef short short8 __attribute__((ext_vector_type(8)));
typedef float f32x4 __attribute__((ext_vector_type(4)));

__device__ __forceinline__ float fast_sigmoid(float x) {
    x = fminf(fmaxf(x, -30.f), 30.f);
    return 1.0f / (1.0f + __expf(-x));
}
__device__ __forceinline__ float fast_tanh(float x) {
    x = fminf(fmaxf(x, -15.f), 15.f);
    float e = __expf(2.0f * x);
    return (e - 1.0f) / (e + 1.0f);
}
__device__ __forceinline__ unsigned short bf16rn(float x) {
    unsigned int u = __float_as_uint(x);
    return (unsigned short)((u + 0x7FFFu + ((u >> 16) & 1u)) >> 16);
}
__device__ __forceinline__ void split2(float x, unsigned short& h, unsigned short& l) {
    h = bf16rn(x);
    float hf = __uint_as_float(((unsigned int)h) << 16);
    l = bf16rn(x - hf);
}

// ---------------------------------------------------------------------------
// Group barrier (16 blocks sharing a row slab; all on one XCD under round-
// robin dispatch since grp = bid&15 and bid&7 selects the XCD). R3-proven
// fence/atomic pattern. Monotonic generation counter in ws (zeroed by wsplit).
// ---------------------------------------------------------------------------
__device__ __forceinline__ void rg_barrier16(int* ctr, int gen) {
    __threadfence();
    __syncthreads();
    if (threadIdx.x == 0) {
        __hip_atomic_fetch_add(ctr, 1, __ATOMIC_RELEASE, __HIP_MEMORY_SCOPE_AGENT);
        while (__hip_atomic_load(ctr, __ATOMIC_ACQUIRE, __HIP_MEMORY_SCOPE_AGENT) < gen * 16) {
            __builtin_amdgcn_s_sleep(2);
        }
    }
    __syncthreads();
    __threadfence();
}

// ---------------------------------------------------------------------------
// K1: proj = embed @ Wi + b (enc mat0 / dec mat1), [28,512]@[512,2048]. Once.
// ---------------------------------------------------------------------------
__global__ __launch_bounds__(256) void proj_kernel(
    const float* __restrict__ enc_embed, const float* __restrict__ enc_Wi, const float* __restrict__ enc_b,
    const float* __restrict__ dec_embed, const float* __restrict__ dec_Wi, const float* __restrict__ dec_b,
    float* __restrict__ enc_proj, float* __restrict__ dec_proj)
{
    __shared__ float emb[V][513];
    int mat = blockIdx.x >> 5;
    int cg  = blockIdx.x & 31;
    int c0  = cg * 64;
    const float* embed = mat ? dec_embed : enc_embed;
    const float* Wi    = mat ? dec_Wi    : enc_Wi;
    const float* bias  = mat ? dec_b     : enc_b;
    float*       proj  = mat ? dec_proj  : enc_proj;
    int tid = threadIdx.x;
    #pragma unroll
    for (int i = 0; i < 14; ++i) {
        int u = tid + i * 256;
        int r = u >> 7, q = u & 127;
        float4 vv = *(const float4*)&embed[r * H + q * 4];
        emb[r][q*4+0] = vv.x; emb[r][q*4+1] = vv.y; emb[r][q*4+2] = vv.z; emb[r][q*4+3] = vv.w;
    }
    __syncthreads();
    int col = c0 + (tid & 63);
    int rg  = tid >> 6;
    float acc[7] = {0,0,0,0,0,0,0};
    for (int k = 0; k < H; ++k) {
        float w = Wi[k * G4 + col];
        #pragma unroll
        for (int r = 0; r < 7; ++r) acc[r] += w * emb[rg*7 + r][k];
    }
    float bb = bias[col];
    #pragma unroll
    for (int r = 0; r < 7; ++r) proj[(rg*7 + r) * G4 + col] = acc[r] + bb;
}

// ---------------------------------------------------------------------------
// K1b: transpose + split Wh (f32 [512][2048]) -> WT_hi/lo (bf16 [2048][512]).
// Also zeroes the 512-int barrier region (ws is poisoned 0xAA every replay).
// ---------------------------------------------------------------------------
__global__ __launch_bounds__(256) void wsplit_kernel(
    const float* __restrict__ encW, const float* __restrict__ decW,
    unsigned short* __restrict__ WTeh, unsigned short* __restrict__ WTel,
    unsigned short* __restrict__ WTdh, unsigned short* __restrict__ WTdl,
    int* bar)
{
    if (blockIdx.x == 0) { bar[threadIdx.x] = 0; bar[threadIdx.x + 256] = 0; }
    __shared__ float tile[64][65];
    int bid = blockIdx.x;
    int mat = bid >> 8;
    int kb  = (bid >> 5) & 7;
    int cb  = bid & 31;
    const float* W = mat ? decW : encW;
    unsigned short* Th = mat ? WTdh : WTeh;
    unsigned short* Tl = mat ? WTdl : WTel;
    int k0 = kb * 64, c0 = cb * 64;
    int tid = threadIdx.x;
    #pragma unroll
    for (int i = 0; i < 4; ++i) {
        int u = tid + i * 256;
        int kk = u >> 4, cq = u & 15;
        float4 vv = *(const float4*)&W[(k0 + kk) * G4 + c0 + cq * 4];
        tile[kk][cq*4+0] = vv.x; tile[kk][cq*4+1] = vv.y;
        tile[kk][cq*4+2] = vv.z; tile[kk][cq*4+3] = vv.w;
    }
    __syncthreads();
    #pragma unroll
    for (int i = 0; i < 4; ++i) {
        int u = tid + i * 256;
        int c = u >> 4, kq = u & 15;
        ushort4 hh, ll;
        float x0 = tile[kq*4+0][c], x1 = tile[kq*4+1][c];
        float x2 = tile[kq*4+2][c], x3 = tile[kq*4+3][c];
        split2(x0, hh.x, ll.x); split2(x1, hh.y, ll.y);
        split2(x2, hh.z, ll.z); split2(x3, hh.w, ll.w);
        size_t off = (size_t)(c0 + c) * 512 + k0 + kq * 4;
        *(ushort4*)&Th[off] = hh;
        *(ushort4*)&Tl[off] = ll;
    }
}

// ---------------------------------------------------------------------------
// Persistent mega-kernel. 256 blocks x 512 threads (8 waves, 2/SIMD).
// grp = bid & 15  -> row slab [grp*16, +16)  (16-block barrier group, 1 XCD)
// cb  = bid >> 4  -> h-col band [cb*32, +32)  (= 128 g-cols across 4 gates)
// Wh slice (128 gcols x 512 k, bf16 hi+lo) persistent in VGPRs (128/lane);
// c state persistent in 1 reg/thread; h slab staged to LDS (bf16 hi/lo,
// XOR-swizzled, full-offset XOR — see bugfix note) each step; 3-term MFMA.
// ---------------------------------------------------------------------------
__global__ __launch_bounds__(512, 2) void vae_mega(
    const int* __restrict__ x, const int* __restrict__ target,
    const float* __restrict__ hidden, const float* __restrict__ eps,
    const float* __restrict__ Wmu, const float* __restrict__ bmu,
    const float* __restrict__ Wlv, const float* __restrict__ blv,
    const float* __restrict__ Wout, const float* __restrict__ bout,
    const float* __restrict__ enc_proj, const float* __restrict__ dec_proj,
    const unsigned short* __restrict__ WTeh, const unsigned short* __restrict__ WTel,
    const unsigned short* __restrict__ WTdh, const unsigned short* __restrict__ WTdl,
    float* __restrict__ hA, float* __restrict__ hB, float* __restrict__ zb,
    int* bar, float* __restrict__ out)
{
    __shared__ __align__(16) unsigned short Ah[16 * 512];
    __shared__ __align__(16) unsigned short Al[16 * 512];
    __shared__ float gt[16 * 132];
    __shared__ float lp[512];

    const int tid = threadIdx.x, bid = blockIdx.x;
    const int grp = bid & 15, cb = bid >> 4;
    const int r0 = grp * 16, hc0 = cb * 32;
    const int wid = tid >> 6, lane = tid & 63;
    const int lr = lane & 15, kg = lane >> 4;
    const int gcolT = (wid >> 1) * 512 + hc0 + (wid & 1) * 16 + lr; // WT row
    const int erow = tid >> 5, ecol = tid & 31;   // epilogue coords
    const int grow = r0 + erow;
    const int gj = hc0 + ecol;
    const int lrow = r0 + cb;                     // this block's logit row
    int* mybar = bar + grp * 32;
    int gen = 0;

    short8 bh[16], bl[16];                        // persistent Wh slice
    // BUGFIX (R5 audit): XOR must apply to the FULL per-ks byte offset.
    // swzA occupies bits 4-6; ks*64 occupies bit 6+, so adding ks*64 AFTER
    // the XOR carries into bit 7 for lanes with (lr&4) and odd ks.
    const int swzA   = (lr & 7) << 4;
    const int abase0 = lr * 1024 + kg * 16;

    float c_reg = hidden[grow * H + gj];          // encoder c0 (=h0=hidden)

    // ---- encoder weights -> VGPRs ----
    {
        const unsigned short* ph = WTeh + (size_t)gcolT * 512 + kg * 8;
        const unsigned short* pl = WTel + (size_t)gcolT * 512 + kg * 8;
        #pragma unroll
        for (int ks = 0; ks < 16; ++ks) {
            bh[ks] = *(const short8*)(ph + ks * 32);
            bl[ks] = *(const short8*)(pl + ks * 32);
        }
    }

    auto stage = [&](const float* hsrc) {
        #pragma unroll
        for (int i = 0; i < 4; ++i) {
            int u = tid + i * 512;
            int row = u >> 7, q = u & 127;
            float4 v4 = *(const float4*)&hsrc[(r0 + row) * H + q * 4];
            ushort4 hh, ll;
            split2(v4.x, hh.x, ll.x); split2(v4.y, hh.y, ll.y);
            split2(v4.z, hh.z, ll.z); split2(v4.w, hh.w, ll.w);
            int off = (row * 1024 + q * 8) ^ ((row & 7) << 4);
            *(ushort4*)((char*)Ah + off) = hh;
            *(ushort4*)((char*)Al + off) = ll;
        }
    };

    auto gemm_gates = [&](const float* proj_, const int* tokp, float* hdst) {
        f32x4 ahh = {0.f,0.f,0.f,0.f}, ahl = {0.f,0.f,0.f,0.f}, alh = {0.f,0.f,0.f,0.f};
        #pragma unroll
        for (int ks = 0; ks < 16; ++ks) {
            int aoff = (abase0 + ks * 64) ^ swzA;          // full-offset XOR
            short8 ah = *(const short8*)((const char*)Ah + aoff);
            short8 al = *(const short8*)((const char*)Al + aoff);
            ahh = __builtin_amdgcn_mfma_f32_16x16x32_bf16(ah, bh[ks], ahh, 0, 0, 0);
            ahl = __builtin_amdgcn_mfma_f32_16x16x32_bf16(ah, bl[ks], ahl, 0, 0, 0);
            alh = __builtin_amdgcn_mfma_f32_16x16x32_bf16(al, bh[ks], alh, 0, 0, 0);
        }
        // C/D: col = lane&15 (block col = wid*16+lr), row = kg*4 + reg
        #pragma unroll
        for (int r = 0; r < 4; ++r)
            gt[(kg * 4 + r) * 132 + wid * 16 + lr] = ahh[r] + ahl[r] + alh[r];
        __syncthreads();
        int tok = tokp ? tokp[grow] : 0;
        const float* pr = proj_ + tok * G4;
        float gi = gt[erow * 132 +       ecol] + pr[gj];
        float gf = gt[erow * 132 +  32 + ecol] + pr[512 + gj];
        float gg = gt[erow * 132 +  64 + ecol] + pr[1024 + gj];
        float go = gt[erow * 132 +  96 + ecol] + pr[1536 + gj];
        float cn = fast_sigmoid(gf) * c_reg + fast_sigmoid(gi) * fast_tanh(gg);
        c_reg = cn;
        hdst[grow * H + gj] = fast_sigmoid(go) * fast_tanh(cn);
    };

    auto logit_partial = [&](const float* hsrc) {
        int v = tid & 31, ks = tid >> 5;
        float lacc = 0.f;
        if (v < V) {
            const float* hr = hsrc + lrow * H + ks * 32;
            const float* wr = Wout + (ks * 32) * V + v;
            #pragma unroll 8
            for (int k = 0; k < 32; ++k) lacc += hr[k] * wr[k * V];
        }
        lp[tid] = lacc;
    };
    auto logit_finish = [&](int lt) {
        if (tid < 32) {
            int v = tid;
            float sum = 0.f;
            #pragma unroll
            for (int ks = 0; ks < 16; ++ks) sum += lp[ks * 32 + v];
            float val = (v < V) ? sum + bout[v] : -INFINITY;
            float m = val;
            #pragma unroll
            for (int s = 16; s >= 1; s >>= 1) m = fmaxf(m, __shfl_xor(m, s, 32));
            float e = (v < V) ? __expf(val - m) : 0.f;
            #pragma unroll
            for (int s = 16; s >= 1; s >>= 1) e += __shfl_xor(e, s, 32);
            float lse = m + __logf(e);
            if (v < V) out[(lt * B + lrow) * V + v] = val - lse;
        }
    };

    // ---- encoder: 256 steps ----
    #pragma unroll 1
    for (int t = 0; t < T; ++t) {
        const float* src = (t == 0) ? hidden : ((t & 1) ? hA : hB);
        float* dst = (t & 1) ? hB : hA;
        stage(src);
        __syncthreads();
        gemm_gates(enc_proj, x + t * B, dst);
        rg_barrier16(mybar, ++gen);
    }

    // ---- latent: mu/lv/z for this thread's (grow, gj); c_reg := z ----
    {
        const float* hr = hB + grow * H;          // encoder final h (t=255 odd)
        float amu = 0.f, alv = 0.f;
        #pragma unroll 4
        for (int k = 0; k < H; ++k) {
            float hv = hr[k];
            amu += hv * Wmu[k * H + gj];
            alv += hv * Wlv[k * H + gj];
        }
        float mu = amu + bmu[gj];
        float lv = alv + blv[gj];
        out[OUT_MU + grow * H + gj] = mu;
        out[OUT_LV + grow * H + gj] = lv;
        float zv = mu + eps[grow * H + gj] * __expf(0.5f * lv);
        zb[grow * H + gj] = zv;
        c_reg = zv;
    }
    // ---- decoder weights -> VGPRs ----
    {
        const unsigned short* ph = WTdh + (size_t)gcolT * 512 + kg * 8;
        const unsigned short* pl = WTdl + (size_t)gcolT * 512 + kg * 8;
        #pragma unroll
        for (int ks = 0; ks < 16; ++ks) {
            bh[ks] = *(const short8*)(ph + ks * 32);
            bl[ks] = *(const short8*)(pl + ks * 32);
        }
    }
    rg_barrier16(mybar, ++gen);

    // ---- decoder: 256 steps, logits of h_{t-1} fused into step t ----
    #pragma unroll 1
    for (int t = 0; t < T; ++t) {
        const float* src = (t == 0) ? zb : ((t & 1) ? hA : hB);
        float* dst = (t & 1) ? hB : hA;
        if (t > 0) logit_partial(src);
        stage(src);
        __syncthreads();
        gemm_gates(dec_proj, (t == 0) ? nullptr : (target + (t - 1) * B), dst);
        if (t > 0) logit_finish(t - 1);
        rg_barrier16(mybar, ++gen);
    }

    // ---- final logits: hs[255] = hB ----
    logit_partial(hB);
    __syncthreads();
    logit_finish(255);
}

// ---------------------------------------------------------------------------
extern "C" void kernel_launch(void* const* d_in, const int* in_sizes, int n_in,
                              void* d_out, int out_size, void* d_ws, size_t ws_size,
                              hipStream_t stream)
{
    const int*   x         = (const int*)  d_in[0];
    const int*   target    = (const int*)  d_in[1];
    const float* hidden    = (const float*)d_in[2];
    const float* eps       = (const float*)d_in[3];
    const float* enc_embed = (const float*)d_in[4];
    const float* enc_Wi    = (const float*)d_in[5];
    const float* enc_Wh    = (const float*)d_in[6];
    const float* enc_b     = (const float*)d_in[7];
    const float* Wmu       = (const float*)d_in[8];
    const float* bmu       = (const float*)d_in[9];
    const float* Wlv       = (const float*)d_in[10];
    const float* blv       = (const float*)d_in[11];
    const float* dec_embed = (const float*)d_in[12];
    const float* dec_Wi    = (const float*)d_in[13];
    const float* dec_Wh    = (const float*)d_in[14];
    const float* dec_b     = (const float*)d_in[15];
    const float* Wout      = (const float*)d_in[16];
    const float* bout      = (const float*)d_in[17];
    float* out = (float*)d_out;
    float* ws  = (float*)d_ws;

    float* enc_proj = ws;                          // 28*2048 f32
    float* dec_proj = enc_proj + V * G4;
    float* hA       = dec_proj + V * G4;           // 256*512 f32 each
    float* hB       = hA + B * H;
    float* zb       = hB + B * H;
    unsigned short* WTeh = (unsigned short*)(zb + B * H);  // 2048*512 bf16 each
    unsigned short* WTel = WTeh + 2048 * 512;
    unsigned short* WTdh = WTel + 2048 * 512;
    unsigned short* WTdl = WTdh + 2048 * 512;
    int* bar = (int*)(WTdl + 2048 * 512);          // 512 ints (16 ctrs, stride 32)

    proj_kernel<<<64, 256, 0, stream>>>(enc_embed, enc_Wi, enc_b,
                                        dec_embed, dec_Wi, dec_b,
                                        enc_proj, dec_proj);
    wsplit_kernel<<<512, 256, 0, stream>>>(enc_Wh, dec_Wh,
                                           WTeh, WTel, WTdh, WTdl, bar);
    vae_mega<<<256, 512, 0, stream>>>(x, target, hidden, eps,
                                      Wmu, bmu, Wlv, blv, Wout, bout,
                                      enc_proj, dec_proj,
                                      WTeh, WTel, WTdh, WTdl,
                                      hA, hB, zb, bar, out);
}